// Round 5
// baseline (250.797 us; speedup 1.0000x reference)
//
#include <hip/hip_runtime.h>
#include <hip/hip_bf16.h>

// GeometricLinear: out[b,i,r] = sum_{j,p} x[b,j,p] * Wc[i,j,p,r] + bias[i,r]
// Wc[i,j,p,r] = STAB[r][p] * weight[i,j,QTAB[r][p]]  (Cl(3,0) Cayley = signed perm)
// => single bf16 GEMM: out[4096][4096] = X[4096][4096] * Wc_bt[4096][4096]^T + bias
// GEMM: 256x256 tile, BK=64, 8 waves (2x4), 8-phase K-split schedule with
// one-phase-ahead fragment prefetch (reads overlap MFMA), counted vmcnt,
// XOR LDS swizzle (0 conflicts), setprio, XCD-aware block swizzle.

#define MDIM 4096
#define NDIM 4096
#define KDIM 4096
#define KTILES 64   // KDIM/64

typedef __attribute__((ext_vector_type(8))) __bf16 bf16x8;
typedef __attribute__((ext_vector_type(4))) float f32x4;
typedef __attribute__((ext_vector_type(8))) unsigned short ushort8;

__device__ __forceinline__ unsigned short f2bf(float f) {
  unsigned int u = __builtin_bit_cast(unsigned int, f);
  u += 0x7fffu + ((u >> 16) & 1u);   // round-to-nearest-even
  return (unsigned short)(u >> 16);
}

// Compile-time Cayley tables (constexpr => folded to immediates under unroll).
static constexpr int QTAB[8][8] = {
  {0,1,2,3,4,5,6,7},
  {1,0,4,5,2,3,7,6},
  {2,4,0,6,1,7,3,5},
  {3,5,6,0,7,1,2,4},
  {4,2,1,7,0,6,5,3},
  {5,3,7,1,6,0,4,2},
  {6,7,3,2,5,4,0,1},
  {7,6,5,4,3,2,1,0},
};
// sign bit to XOR into the bf16 (0x8000 where STAB == -1)
static constexpr unsigned short SBIT[8][8] = {
  {0,0,0,0,0x8000,0x8000,0x8000,0x8000},
  {0,0,0x8000,0x8000,0,0,0x8000,0x8000},
  {0,0,0,0x8000,0x8000,0,0,0},
  {0,0,0,0,0x8000,0x8000,0x8000,0x8000},
  {0,0,0x8000,0,0,0x8000,0,0},
  {0,0,0x8000,0x8000,0,0,0x8000,0x8000},
  {0,0,0,0x8000,0x8000,0,0,0},
  {0,0,0x8000,0,0,0x8000,0,0},
};

// ---- kernel 1: cast x (f32) -> Xb (bf16) ----
__global__ __launch_bounds__(256) void cast_x_kernel(
    const float* __restrict__ X, unsigned short* __restrict__ Xb) {
  const size_t t = (size_t)blockIdx.x * 256 + threadIdx.x;
  const float4* p = (const float4*)(X + t * 8);
  float4 a = p[0], b = p[1];
  ushort8 o;
  o[0] = f2bf(a.x); o[1] = f2bf(a.y); o[2] = f2bf(a.z); o[3] = f2bf(a.w);
  o[4] = f2bf(b.x); o[5] = f2bf(b.y); o[6] = f2bf(b.z); o[7] = f2bf(b.w);
  *(ushort8*)(Xb + t * 8) = o;
}

// ---- kernel 2: build Wb[n][k], one thread per (i,j), ALL indices static ----
__global__ __launch_bounds__(256) void build_wc_kernel(
    const float* __restrict__ W, unsigned short* __restrict__ Wb) {
  const int t = blockIdx.x * 256 + threadIdx.x;   // t = i*512 + j
  const int i = t >> 9;
  const int j = t & 511;
  const float4 w0 = *(const float4*)(W + (size_t)t * 8);
  const float4 w1 = *(const float4*)(W + (size_t)t * 8 + 4);
  const unsigned short b[8] = {f2bf(w0.x), f2bf(w0.y), f2bf(w0.z), f2bf(w0.w),
                               f2bf(w1.x), f2bf(w1.y), f2bf(w1.z), f2bf(w1.w)};
#pragma unroll
  for (int r = 0; r < 8; ++r) {
    ushort8 o;
#pragma unroll
    for (int p = 0; p < 8; ++p)
      o[p] = (unsigned short)(b[QTAB[r][p]] ^ SBIT[r][p]);
    *(ushort8*)(Wb + (size_t)(i * 8 + r) * KDIM + j * 8) = o;
  }
}

// ---- kernel 3: 256x256 8-phase bf16 GEMM, C = A*B^T + bias ----
typedef const __attribute__((address_space(1))) unsigned int as1_uint;
typedef __attribute__((address_space(3))) unsigned int as3_uint;

__device__ __forceinline__ void gload_lds16(const unsigned short* g,
                                            unsigned short* l) {
  __builtin_amdgcn_global_load_lds((as1_uint*)g, (as3_uint*)l, 16, 0, 0);
}

// Stage one half-tile [256 rows][32 K] (16 KiB) -> LDS slot (linear dest).
// XOR swizzle: LDS granule (row, s) holds k-seg q = s ^ ((row>>1)&3), applied
// by permuting the per-lane GLOBAL source column; reads use the same XOR.
__device__ __forceinline__ void stage_half(
    const unsigned short* __restrict__ G, int gbase_row, int tile, int kh,
    unsigned short* lds_slot, int wid, int lane) {
  const int colswz = ((lane & 3) ^ ((lane >> 3) & 3)) * 8;
#pragma unroll
  for (int q = 0; q < 2; ++q) {
    const int c = wid * 2 + q;                       // chunk 0..15, 16 rows each
    const unsigned short* src = G
        + (size_t)(gbase_row + c * 16 + (lane >> 2)) * KDIM
        + tile * 64 + kh * 32 + colswz;
    gload_lds16(src, lds_slot + c * 512);            // wave-uniform base
  }
}

#define BAR()  asm volatile("s_barrier" ::: "memory")
#define VM6()  asm volatile("s_waitcnt vmcnt(6)" ::: "memory")
#define VM0()  asm volatile("s_waitcnt vmcnt(0)" ::: "memory")

// Fragment reads (prefetch into alternate register sets; statically named).
#define RDA(dst, bufb, kk, mh) do {                                           \
    _Pragma("unroll") for (int mi_ = 0; mi_ < 4; ++mi_)                       \
      dst[mi_] = *(const bf16x8*)(&lds[(bufb)*4 + (kk)][0]                    \
          + ((wm)*128 + ((mh)*4 + mi_)*16 + fr)*32 + fqs*8);                  \
  } while (0)
#define RDB_(dst, bufb, kk) do {                                              \
    _Pragma("unroll") for (int ni_ = 0; ni_ < 4; ++ni_)                       \
      dst[ni_] = *(const bf16x8*)(&lds[(bufb)*4 + 2 + (kk)][0]                \
          + ((wn)*64 + ni_*16 + fr)*32 + fqs*8);                              \
  } while (0)
#define MFMA16(afv, bv, mh) do {                                              \
    __builtin_amdgcn_s_setprio(1);                                            \
    _Pragma("unroll") for (int mi_ = 0; mi_ < 4; ++mi_) {                     \
      _Pragma("unroll") for (int ni_ = 0; ni_ < 4; ++ni_)                     \
        acc[(mh)*4 + mi_][ni_] = __builtin_amdgcn_mfma_f32_16x16x32_bf16(     \
            afv[mi_], bv[ni_], acc[(mh)*4 + mi_][ni_], 0, 0, 0);              \
    }                                                                         \
    __builtin_amdgcn_s_setprio(0);                                            \
  } while (0)

__global__ __launch_bounds__(512, 2) void gemm_bt_bias(
    const unsigned short* __restrict__ A,   // [M][K] bf16 bits
    const unsigned short* __restrict__ B,   // [N][K] bf16 bits
    const float* __restrict__ bias,         // [N]
    float* __restrict__ C) {                // [M][N] f32
  // 8 half-tile slots of 16 KiB: slot = buf*4 + mat*2 + khalf  (mat: A=0,B=1)
  __shared__ unsigned short lds[8][8192];   // 128 KiB

  const int tid = threadIdx.x;
  const int wid = tid >> 6;        // 0..7
  const int lane = tid & 63;
  const int wm = wid >> 2;         // 0..1 : wave row-half (128 rows)
  const int wn = wid & 3;          // 0..3 : wave col-quarter (64 cols)
  const int fr = lane & 15;
  const int fq = lane >> 4;
  const int fqs = fq ^ ((fr >> 1) & 3);   // swizzled k-seg for LDS reads

  // XCD-aware bijective swizzle (256 blocks, 256 % 8 == 0)
  const int raw = blockIdx.x;
  const int wg = (raw & 7) * 32 + (raw >> 3);
  const int brow = (wg >> 4) * 256;
  const int bcol = (wg & 15) * 256;

  f32x4 acc[8][4];
#pragma unroll
  for (int m = 0; m < 8; ++m)
#pragma unroll
    for (int n = 0; n < 4; ++n) acc[m][n] = (f32x4){0.f, 0.f, 0.f, 0.f};
  bf16x8 afA[4], afB[4], bU[4], bV[4];

  // Prologue: tile0 all 4 halves, tile1 {Bk0, Ak0, Bk1}; tile1.Ak1 comes in P1.
  stage_half(A, brow, 0, 0, &lds[0][0], wid, lane);
  stage_half(A, brow, 0, 1, &lds[1][0], wid, lane);
  stage_half(B, bcol, 0, 0, &lds[2][0], wid, lane);
  stage_half(B, bcol, 0, 1, &lds[3][0], wid, lane);
  stage_half(A, brow, 1, 0, &lds[4][0], wid, lane);
  stage_half(B, bcol, 1, 0, &lds[6][0], wid, lane);
  stage_half(B, bcol, 1, 1, &lds[7][0], wid, lane);
  VM6();   // tile0's 8 loads landed
  BAR();
  RDA(afA, 0, 0, 0);   // pre-read P1 operands
  RDB_(bU, 0, 0);

  // Main loop: iteration i computes tiles 2i (buf0) and 2i+1 (buf1).
  // Per phase: stage -> [vmcnt] -> BAR -> prefetch(p+1 regs) + 16 MFMA -> BAR.
  for (int i = 0; i < KTILES / 2 - 1; ++i) {
    const int t0 = 2 * i, t1 = 2 * i + 1;
    // P1 (buf0,kk0,mh0)
    stage_half(A, brow, t1, 1, &lds[5][0], wid, lane);
    BAR(); RDA(afB, 0, 0, 1);                  MFMA16(afA, bU, 0); BAR();
    // P2 (buf0,kk0,mh1)
    stage_half(B, bcol, t0 + 2, 0, &lds[2][0], wid, lane);
    BAR(); RDA(afA, 0, 1, 0); RDB_(bV, 0, 1);  MFMA16(afB, bU, 1); BAR();
    // P3 (buf0,kk1,mh0)
    stage_half(A, brow, t0 + 2, 0, &lds[0][0], wid, lane);
    BAR(); RDA(afB, 0, 1, 1);                  MFMA16(afA, bV, 0); BAR();
    // P4 (buf0,kk1,mh1)
    stage_half(B, bcol, t0 + 2, 1, &lds[3][0], wid, lane);
    VM6();   // buf1 (tile t1) fully landed
    BAR(); RDA(afA, 1, 0, 0); RDB_(bU, 1, 0);  MFMA16(afB, bV, 1); BAR();
    // P5 (buf1,kk0,mh0)
    stage_half(A, brow, t0 + 2, 1, &lds[1][0], wid, lane);
    BAR(); RDA(afB, 1, 0, 1);                  MFMA16(afA, bU, 0); BAR();
    // P6 (buf1,kk0,mh1)
    stage_half(B, bcol, t1 + 2, 0, &lds[6][0], wid, lane);
    BAR(); RDA(afA, 1, 1, 0); RDB_(bV, 1, 1);  MFMA16(afB, bU, 1); BAR();
    // P7 (buf1,kk1,mh0)
    stage_half(A, brow, t1 + 2, 0, &lds[4][0], wid, lane);
    BAR(); RDA(afB, 1, 1, 1);                  MFMA16(afA, bV, 0); BAR();
    // P8 (buf1,kk1,mh1)
    stage_half(B, bcol, t1 + 2, 1, &lds[7][0], wid, lane);
    VM6();   // buf0 (tile t0+2) fully landed
    BAR(); RDA(afA, 0, 0, 0); RDB_(bU, 0, 0);  MFMA16(afB, bV, 1); BAR();
  }

  // Epilogue: tiles 62 (buf0), 63 (buf1); only the lagging tile63.Ak1 stage.
  stage_half(A, brow, KTILES - 1, 1, &lds[5][0], wid, lane);
  BAR(); RDA(afB, 0, 0, 1);                  MFMA16(afA, bU, 0); BAR();
  BAR(); RDA(afA, 0, 1, 0); RDB_(bV, 0, 1);  MFMA16(afB, bU, 1); BAR();
  BAR(); RDA(afB, 0, 1, 1);                  MFMA16(afA, bV, 0); BAR();
  VM0();   // slot5 (tile63.Ak1) and everything else landed
  BAR(); RDA(afA, 1, 0, 0); RDB_(bU, 1, 0);  MFMA16(afB, bV, 1); BAR();
  BAR(); RDA(afB, 1, 0, 1);                  MFMA16(afA, bU, 0); BAR();
  BAR(); RDA(afA, 1, 1, 0); RDB_(bV, 1, 1);  MFMA16(afB, bU, 1); BAR();
  BAR(); RDA(afB, 1, 1, 1);                  MFMA16(afA, bV, 0); BAR();
  BAR();                                     MFMA16(afB, bV, 1); BAR();

  // C-write: D layout col = lane&15, row = (lane>>4)*4 + j (m89-verified)
#pragma unroll
  for (int n = 0; n < 4; ++n) {
    const int col = bcol + wn * 64 + n * 16 + fr;
    const float bvs = bias[col];
#pragma unroll
    for (int m = 0; m < 8; ++m) {
      const int row0 = brow + wm * 128 + m * 16 + fq * 4;
#pragma unroll
      for (int j = 0; j < 4; ++j)
        C[(size_t)(row0 + j) * NDIM + col] = acc[m][n][j] + bvs;
    }
  }
}

extern "C" void kernel_launch(void* const* d_in, const int* in_sizes, int n_in,
                              void* d_out, int out_size, void* d_ws, size_t ws_size,
                              hipStream_t stream) {
  const float* x = (const float*)d_in[0];     // [4096,512,8]
  const float* w = (const float*)d_in[1];     // [512,512,8]
  const float* bias = (const float*)d_in[2];  // [512,8]
  float* out = (float*)d_out;                 // [4096,512,8]

  unsigned short* Xb = (unsigned short*)d_ws;           // 32 MiB
  unsigned short* Wb = Xb + (size_t)MDIM * KDIM;        // 32 MiB

  cast_x_kernel<<<8192, 256, 0, stream>>>(x, Xb);
  build_wc_kernel<<<1024, 256, 0, stream>>>(w, Wb);
  gemm_bt_bias<<<256, 512, 0, stream>>>(Xb, Wb, bias, out);
}

// Round 8
// 238.182 us; speedup vs baseline: 1.0530x; 1.0530x over previous
//
#include <hip/hip_runtime.h>
#include <hip/hip_bf16.h>

// GeometricLinear: out[b,i,r] = sum_{j,p} x[b,j,p] * Wc[i,j,p,r] + bias[i,r]
// Wc[i,j,p,r] = STAB[r][p] * weight[i,j,QTAB[r][p]]  (Cl(3,0) Cayley = signed perm)
// => single bf16 GEMM: out[4096][4096] = X[4096][4096] * Wc_bt[4096][4096]^T + bias
// GEMM: 256x256 tile, BK=64, 8 waves (2x4), 8-block SINGLE-BARRIER schedule:
// block = [stage 1 half-tile; (vmcnt(6) on even blocks); s_barrier;
//          ds_read next block's fragments; 16 MFMA].
// Slot ledger proven: stage@q only where last consuming read <= q-2 (barrier-
// ordered); landing covered by vmcnt checkpoint before first read.

#define MDIM 4096
#define NDIM 4096
#define KDIM 4096
#define KTILES 64   // KDIM/64

typedef __attribute__((ext_vector_type(8))) __bf16 bf16x8;
typedef __attribute__((ext_vector_type(4))) float f32x4;
typedef __attribute__((ext_vector_type(8))) unsigned short ushort8;

__device__ __forceinline__ unsigned short f2bf(float f) {
  unsigned int u = __builtin_bit_cast(unsigned int, f);
  u += 0x7fffu + ((u >> 16) & 1u);   // round-to-nearest-even
  return (unsigned short)(u >> 16);
}

// Compile-time Cayley tables (constexpr => folded to immediates under unroll).
static constexpr int QTAB[8][8] = {
  {0,1,2,3,4,5,6,7},
  {1,0,4,5,2,3,7,6},
  {2,4,0,6,1,7,3,5},
  {3,5,6,0,7,1,2,4},
  {4,2,1,7,0,6,5,3},
  {5,3,7,1,6,0,4,2},
  {6,7,3,2,5,4,0,1},
  {7,6,5,4,3,2,1,0},
};
// sign bit to XOR into the bf16 (0x8000 where STAB == -1)
static constexpr unsigned short SBIT[8][8] = {
  {0,0,0,0,0x8000,0x8000,0x8000,0x8000},
  {0,0,0x8000,0x8000,0,0,0x8000,0x8000},
  {0,0,0,0x8000,0x8000,0,0,0},
  {0,0,0,0,0x8000,0x8000,0x8000,0x8000},
  {0,0,0x8000,0,0,0x8000,0,0},
  {0,0,0x8000,0x8000,0,0,0x8000,0x8000},
  {0,0,0,0x8000,0x8000,0,0,0},
  {0,0,0x8000,0,0,0x8000,0,0},
};

// ---- kernel 1: cast x (f32) -> Xb (bf16) ----
__global__ __launch_bounds__(256) void cast_x_kernel(
    const float* __restrict__ X, unsigned short* __restrict__ Xb) {
  const size_t t = (size_t)blockIdx.x * 256 + threadIdx.x;
  const float4* p = (const float4*)(X + t * 8);
  float4 a = p[0], b = p[1];
  ushort8 o;
  o[0] = f2bf(a.x); o[1] = f2bf(a.y); o[2] = f2bf(a.z); o[3] = f2bf(a.w);
  o[4] = f2bf(b.x); o[5] = f2bf(b.y); o[6] = f2bf(b.z); o[7] = f2bf(b.w);
  *(ushort8*)(Xb + t * 8) = o;
}

// ---- kernel 2: build Wb[n][k], one thread per (i,j), ALL indices static ----
__global__ __launch_bounds__(256) void build_wc_kernel(
    const float* __restrict__ W, unsigned short* __restrict__ Wb) {
  const int t = blockIdx.x * 256 + threadIdx.x;   // t = i*512 + j
  const int i = t >> 9;
  const int j = t & 511;
  const float4 w0 = *(const float4*)(W + (size_t)t * 8);
  const float4 w1 = *(const float4*)(W + (size_t)t * 8 + 4);
  const unsigned short b[8] = {f2bf(w0.x), f2bf(w0.y), f2bf(w0.z), f2bf(w0.w),
                               f2bf(w1.x), f2bf(w1.y), f2bf(w1.z), f2bf(w1.w)};
#pragma unroll
  for (int r = 0; r < 8; ++r) {
    ushort8 o;
#pragma unroll
    for (int p = 0; p < 8; ++p)
      o[p] = (unsigned short)(b[QTAB[r][p]] ^ SBIT[r][p]);
    *(ushort8*)(Wb + (size_t)(i * 8 + r) * KDIM + j * 8) = o;
  }
}

// ---- kernel 3: 256x256 single-barrier 8-block bf16 GEMM, C = A*B^T + bias ----
typedef const __attribute__((address_space(1))) unsigned int as1_uint;
typedef __attribute__((address_space(3))) unsigned int as3_uint;

__device__ __forceinline__ void gload_lds16(const unsigned short* g,
                                            unsigned short* l) {
  __builtin_amdgcn_global_load_lds((as1_uint*)g, (as3_uint*)l, 16, 0, 0);
}

// Stage one half-tile [256 rows][32 K] (16 KiB) -> LDS slot (linear dest).
// XOR swizzle: LDS granule (row, s) holds k-seg q = s ^ ((row>>1)&3), applied
// by permuting the per-lane GLOBAL source column; reads use the same XOR.
__device__ __forceinline__ void stage_half(
    const unsigned short* __restrict__ G, int gbase_row, int tile, int kh,
    unsigned short* lds_slot, int wid, int lane) {
  const int colswz = ((lane & 3) ^ ((lane >> 3) & 3)) * 8;
#pragma unroll
  for (int q = 0; q < 2; ++q) {
    const int c = wid * 2 + q;                       // chunk 0..15, 16 rows each
    const unsigned short* src = G
        + (size_t)(gbase_row + c * 16 + (lane >> 2)) * KDIM
        + tile * 64 + kh * 32 + colswz;
    gload_lds16(src, lds_slot + c * 512);            // wave-uniform base
  }
}

#define BAR()  asm volatile("s_barrier" ::: "memory")
#define VM6()  asm volatile("s_waitcnt vmcnt(6)" ::: "memory")
#define VM4()  asm volatile("s_waitcnt vmcnt(4)" ::: "memory")
#define VM0()  asm volatile("s_waitcnt vmcnt(0)" ::: "memory")
#define NOP_() (void)0

// Fragment reads into statically-named alternating register sets.
#define RDA(dst, bufb, kk, mh) do {                                           \
    _Pragma("unroll") for (int mi_ = 0; mi_ < 4; ++mi_)                       \
      dst[mi_] = *(const bf16x8*)(&lds[(bufb)*4 + (kk)][0]                    \
          + ((wm)*128 + ((mh)*4 + mi_)*16 + fr)*32 + fqs*8);                  \
  } while (0)
#define RDB_(dst, bufb, kk) do {                                              \
    _Pragma("unroll") for (int ni_ = 0; ni_ < 4; ++ni_)                       \
      dst[ni_] = *(const bf16x8*)(&lds[(bufb)*4 + 2 + (kk)][0]                \
          + ((wn)*64 + ni_*16 + fr)*32 + fqs*8);                              \
  } while (0)
#define MFMA16(afv, bv, mh) do {                                              \
    __builtin_amdgcn_s_setprio(1);                                            \
    _Pragma("unroll") for (int mi_ = 0; mi_ < 4; ++mi_) {                     \
      _Pragma("unroll") for (int ni_ = 0; ni_ < 4; ++ni_)                     \
        acc[(mh)*4 + mi_][ni_] = __builtin_amdgcn_mfma_f32_16x16x32_bf16(     \
            afv[mi_], bv[ni_], acc[(mh)*4 + mi_][ni_], 0, 0, 0);              \
    }                                                                         \
    __builtin_amdgcn_s_setprio(0);                                            \
  } while (0)

// One block: stage -> [vmcnt] -> BAR -> read next block's frags -> MFMA this.
#define BLK(STAGE_STMT, VM_STMT, READ_STMT, afv, bv, mh) do {                 \
    STAGE_STMT;                                                               \
    VM_STMT;                                                                  \
    BAR();                                                                    \
    READ_STMT;                                                                \
    MFMA16(afv, bv, mh);                                                      \
  } while (0)

__global__ __launch_bounds__(512, 2) void gemm_bt_bias(
    const unsigned short* __restrict__ A,   // [M][K] bf16 bits
    const unsigned short* __restrict__ B,   // [N][K] bf16 bits
    const float* __restrict__ bias,         // [N]
    float* __restrict__ C) {                // [M][N] f32
  // 8 half-tile slots of 16 KiB: slot = buf*4 + mat*2 + khalf  (mat: A=0,B=1)
  __shared__ unsigned short lds[8][8192];   // 128 KiB

  const int tid = threadIdx.x;
  const int wid = tid >> 6;        // 0..7
  const int lane = tid & 63;
  const int wm = wid >> 2;         // 0..1 : wave row-half (128 rows)
  const int wn = wid & 3;          // 0..3 : wave col-quarter (64 cols)
  const int fr = lane & 15;
  const int fq = lane >> 4;
  const int fqs = fq ^ ((fr >> 1) & 3);   // swizzled k-seg for LDS reads

  // XCD-aware bijective swizzle (256 blocks, 256 % 8 == 0)
  const int raw = blockIdx.x;
  const int wg = (raw & 7) * 32 + (raw >> 3);
  const int brow = (wg >> 4) * 256;
  const int bcol = (wg & 15) * 256;

  f32x4 acc[8][4];
#pragma unroll
  for (int m = 0; m < 8; ++m)
#pragma unroll
    for (int n = 0; n < 4; ++n) acc[m][n] = (f32x4){0.f, 0.f, 0.f, 0.f};
  bf16x8 afA[4], afB[4], bU[4], bV[4];

  // Prologue: stage tile0 {A0,B0,A1,B1} + A(1,k0); vmcnt(6) -> tile0 k0 ready.
  stage_half(A, brow, 0, 0, &lds[0][0], wid, lane);
  stage_half(B, bcol, 0, 0, &lds[2][0], wid, lane);
  stage_half(A, brow, 0, 1, &lds[1][0], wid, lane);
  stage_half(B, bcol, 0, 1, &lds[3][0], wid, lane);
  stage_half(A, brow, 1, 0, &lds[4][0], wid, lane);
  VM6();   // 10 in flight -> oldest 4 (slots 0,2) landed
  BAR();
  RDA(afA, 0, 0, 0);
  RDB_(bU, 0, 0);

  // Main loop: iter i computes tiles 2i (buf0) and 2i+1 (buf1).
  // Stages: P1:s6<-B(t1,0) P2:s5<-A(t1,1) P3:s7<-B(t1,1) P4:s0<-A(t0+2,0)
  //         P5:s2<-B(t0+2,0) P6:s1<-A(t0+2,1) P7:s3<-B(t0+2,1) P8:s4<-A(t1+2,0)
  // vmcnt(6) on even blocks drains the 2 stages needed by that block's reads.
  for (int i = 0; i < KTILES / 2 - 1; ++i) {
    const int t1 = 2 * i + 1, tn0 = 2 * i + 2, tn1 = 2 * i + 3;
    BLK(stage_half(B, bcol, t1, 0, &lds[6][0], wid, lane), NOP_(),
        RDA(afB, 0, 0, 1),                    afA, bU, 0);                // P1
    BLK(stage_half(A, brow, t1, 1, &lds[5][0], wid, lane), VM6(),
        { RDA(afA, 0, 1, 0); RDB_(bV, 0, 1); }, afB, bU, 1);              // P2
    BLK(stage_half(B, bcol, t1, 1, &lds[7][0], wid, lane), NOP_(),
        RDA(afB, 0, 1, 1),                    afA, bV, 0);                // P3
    BLK(stage_half(A, brow, tn0, 0, &lds[0][0], wid, lane), VM6(),
        { RDA(afA, 1, 0, 0); RDB_(bU, 1, 0); }, afB, bV, 1);              // P4
    BLK(stage_half(B, bcol, tn0, 0, &lds[2][0], wid, lane), NOP_(),
        RDA(afB, 1, 0, 1),                    afA, bU, 0);                // P5
    BLK(stage_half(A, brow, tn0, 1, &lds[1][0], wid, lane), VM6(),
        { RDA(afA, 1, 1, 0); RDB_(bV, 1, 1); }, afB, bU, 1);              // P6
    BLK(stage_half(B, bcol, tn0, 1, &lds[3][0], wid, lane), NOP_(),
        RDA(afB, 1, 1, 1),                    afA, bV, 0);                // P7
    BLK(stage_half(A, brow, tn1, 0, &lds[4][0], wid, lane), VM6(),
        { RDA(afA, 0, 0, 0); RDB_(bU, 0, 0); }, afB, bV, 1);              // P8
  }

  // Epilogue pair (tiles 62, 63): only tile-63 B/A-k1 stages remain.
  BLK(stage_half(B, bcol, KTILES - 1, 0, &lds[6][0], wid, lane), NOP_(),
      RDA(afB, 0, 0, 1),                    afA, bU, 0);                  // P1e
  BLK(stage_half(A, brow, KTILES - 1, 1, &lds[5][0], wid, lane), VM6(),
      { RDA(afA, 0, 1, 0); RDB_(bV, 0, 1); }, afB, bU, 1);                // P2e
  BLK(stage_half(B, bcol, KTILES - 1, 1, &lds[7][0], wid, lane), NOP_(),
      RDA(afB, 0, 1, 1),                    afA, bV, 0);                  // P3e
  BLK(NOP_(), VM4(),
      { RDA(afA, 1, 0, 0); RDB_(bU, 1, 0); }, afB, bV, 1);                // P4e
  BLK(NOP_(), NOP_(),
      RDA(afB, 1, 0, 1),                    afA, bU, 0);                  // P5e
  BLK(NOP_(), VM0(),
      { RDA(afA, 1, 1, 0); RDB_(bV, 1, 1); }, afB, bU, 1);                // P6e
  BLK(NOP_(), NOP_(),
      RDA(afB, 1, 1, 1),                    afA, bV, 0);                  // P7e
  BLK(NOP_(), NOP_(), NOP_(),               afB, bV, 1);                  // P8e

  // C-write: D layout col = lane&15, row = (lane>>4)*4 + j (m89-verified)
#pragma unroll
  for (int n = 0; n < 4; ++n) {
    const int col = bcol + wn * 64 + n * 16 + fr;
    const float bvs = bias[col];
#pragma unroll
    for (int m = 0; m < 8; ++m) {
      const int row0 = brow + wm * 128 + m * 16 + fq * 4;
#pragma unroll
      for (int j = 0; j < 4; ++j)
        C[(size_t)(row0 + j) * NDIM + col] = acc[m][n][j] + bvs;
    }
  }
}

extern "C" void kernel_launch(void* const* d_in, const int* in_sizes, int n_in,
                              void* d_out, int out_size, void* d_ws, size_t ws_size,
                              hipStream_t stream) {
  const float* x = (const float*)d_in[0];     // [4096,512,8]
  const float* w = (const float*)d_in[1];     // [512,512,8]
  const float* bias = (const float*)d_in[2];  // [512,8]
  float* out = (float*)d_out;                 // [4096,512,8]

  unsigned short* Xb = (unsigned short*)d_ws;           // 32 MiB
  unsigned short* Wb = Xb + (size_t)MDIM * KDIM;        // 32 MiB

  cast_x_kernel<<<8192, 256, 0, stream>>>(x, Xb);
  build_wc_kernel<<<1024, 256, 0, stream>>>(w, Wb);
  gemm_bt_bias<<<256, 512, 0, stream>>>(Xb, Wb, bias, out);
}